// Round 10
// baseline (243.217 us; speedup 1.0000x reference)
//
#include <hip/hip_runtime.h>
#include <hip/hip_bf16.h>
#include <cmath>

typedef __bf16 bf16_t;
typedef __attribute__((ext_vector_type(8))) __bf16 bfrag;   // 8 bf16 = 4 VGPRs (MFMA A/B frag)
typedef __attribute__((ext_vector_type(4))) __bf16 bf16x4;  // 8B packed store
typedef __attribute__((ext_vector_type(4))) float f32x4;    // MFMA C/D frag

#define SEQ    4096
#define NDIM   1024
#define NHEAD  16
#define HD     64
#define NBATCH 2
#define MROWS  (NBATCH * SEQ)   // 8192
#define LQK    2048             // fused Q|K row stride
#define PSTR   76               // Pw key-stride (conflict-free b64 writes)
// softmax scale 1/8 times log2(e): scores land in exp2 domain (R7)
#define QSC    0.1803368801111f
// exp2f lowers to v_exp_f32 (gfx950 exp IS base-2); __exp2f does not exist in HIP
#define EXP2(x) exp2f(x)

// async 16B global -> LDS (m97 pattern). l must be wave-uniform; lane i lands at l + i*16.
__device__ __forceinline__ void gload_lds16(const bf16_t* g, bf16_t* l) {
    __builtin_amdgcn_global_load_lds(
        (const __attribute__((address_space(1))) unsigned int*)g,
        (__attribute__((address_space(3))) unsigned int*)l,
        16, 0, 0);
}

// raw workgroup barrier WITHOUT the vmcnt(0)/lgkmcnt(0) drain of __syncthreads.
__device__ __forceinline__ void block_sync() {
    asm volatile("" ::: "memory");
    __builtin_amdgcn_s_barrier();
    asm volatile("" ::: "memory");
}
#define VMC(n)  asm volatile("s_waitcnt vmcnt(" #n ")" ::: "memory")

__device__ __forceinline__ bfrag ldsfrag(const bf16_t* region, int R, int quad)
{
    const int off = (R * 64 + quad * 16) ^ (((R >> 3) & 1) << 5);   // bytes
    return *(const bfrag*)((const char*)region + off);
}

// stage 4 KiB (64 rows x 64 B) of a 128-row x 32-el LDS region with 256
// threads: linear DMA dest, pre-swizzled global source (byte ^= ((byte>>9)&1)
// <<5). sub=0 -> rows 0..63, sub=1 -> rows 64..127. One gload_lds16 per
// thread per call. r = loff>>6 is deliberately UNMASKED so sub=1 keeps the
// +64 row base (the R2 bug class).
__device__ __forceinline__ void stage4k(const bf16_t* __restrict__ G, int ldg,
                                        int grow0, int gk0, bf16_t* region,
                                        int sub, int tid)
{
    const int poff = sub * 4096 + tid * 16;             // dest byte in region (linear)
    const int loff = poff ^ (((poff >> 9) & 1) << 5);   // logical byte (pre-swizzled src)
    const int r    = loff >> 6;                         // row 0..127 (keeps sub*64)
    const int cb   = loff & 63;
    const bf16_t* src = G + (size_t)(grow0 + r) * ldg + gk0 + (cb >> 1);
    gload_lds16(src, region + ((sub * 4096 + (tid >> 6) * 1024) >> 1));
}

// ---------------------------------------------------------------------------
// 2-phase 128x128 GEMM, 256 thr / 4 waves, 4 blocks/CU (R10).
//   C = A[M,K] @ W[N,K]^T + bias; V-range (col>=2048) written transposed.
// Mechanism: registers (56 VGPR + 64 AGPR = 120) cap the CU at 16 waves;
// 4x 4-wave blocks give 4 INDEPENDENT K-loops per CU -- block-scoped
// barrier/vmcnt stalls of one block overlap other blocks' compute (the
// m97 cross-block mechanism; 8-wave blocks max out at 2 blocks/CU).
// LDS 2 x (A 4096 + B 4096) els = 32 KiB -> 4 blocks = 128 <= 160 KiB.
// Waves 2x2: wm=wid>>1 (64-row half), wn=wid&1 (64-col half); per-wave
// 64x64 out, acc[4][4]; ph1 rows 0-31 (m 0,1), ph2 rows 32-63 (m 2,3).
// vmcnt ledger (per K-tile: A 2 + B 2 stage4k calls):
//   prologue A0(2)+B0(2)+B1(2); wait A0,B0 -> VMC(2).
//   end ph2(t): queue = [B(t+1):2, A(t+1):2, B(t+2):2]; next ph1 reads
//   A(t+1),B(t+1) -> VMC(2); t >= nt-2 -> VMC(0).
// WAR publication scheme identical to the R6-verified one (stage lands >=1
// barrier after dest region's last read; that read's lgkmcnt(0) precedes
// the prior phase's MFMA).
// ---------------------------------------------------------------------------
template <typename OT>
__global__ __launch_bounds__(256, 4)
void gemm4w(const bf16_t* __restrict__ A, int lda,
            const bf16_t* __restrict__ W,
            const float* __restrict__ b0p, const float* __restrict__ b1p,
            const float* __restrict__ b2p, float qscale,
            OT* __restrict__ C, int ldc, int K,
            bf16_t* __restrict__ VtOut, int nbx)
{
    constexpr int ABUF = 4096;        // A els per buf (128 rows x 32)
    constexpr int BBUF = 4096;        // B els per buf (128 rows x 32)
    constexpr int BUF  = ABUF + BBUF;
    __shared__ __align__(1024) bf16_t LSD[2 * BUF];   // 32 KiB

    const int tid  = threadIdx.x;
    const int lane = tid & 63;
    const int n16  = lane & 15;
    const int quad = lane >> 4;
    const int wid  = tid >> 6;            // 0..3
    const int wm   = wid >> 1;            // 0..1 (64-row half)
    const int wn   = wid & 1;             // 0..1 (64-col half)

    // bijective XCD swizzle (nwg % 8 == 0 for both grids used)
    const int nwg = (int)gridDim.x;
    const int f   = (int)blockIdx.x;
    const int swz = (f & 7) * (nwg >> 3) + (f >> 3);
    const int bx  = swz % nbx;
    const int by  = swz / nbx;
    const int row0 = by * 128;
    const int col0 = bx * 128;
    const int nt   = K >> 5;              // K-tiles of 32 (nt >= 3)

    f32x4 acc[4][4];
#pragma unroll
    for (int m = 0; m < 4; m++)
#pragma unroll
        for (int j = 0; j < 4; j++) acc[m][j] = (f32x4){0.f, 0.f, 0.f, 0.f};

    // ---- prologue: A(0), B(0) -> buf0; B(1) -> buf1 (A(1) staged at t=0 ph1)
    {
        bf16_t* A0 = &LSD[0];
        bf16_t* B0 = &LSD[ABUF];
        bf16_t* B1 = &LSD[BUF + ABUF];
        stage4k(A, lda, row0, 0, A0, 0, tid);
        stage4k(A, lda, row0, 0, A0, 1, tid);
        stage4k(W, K, col0, 0, B0, 0, tid);
        stage4k(W, K, col0, 0, B0, 1, tid);
        stage4k(W, K, col0, 32, B1, 0, tid);
        stage4k(W, K, col0, 32, B1, 1, tid);
    }
    VMC(2);   // A0,B0 landed; B1 may fly. Barrier at ph1 publishes across waves.

    for (int t = 0; t < nt; ++t) {
        bf16_t* Ab  = &LSD[(t & 1) * BUF];
        bf16_t* Bb  = Ab + ABUF;
        bf16_t* AbN = &LSD[((t & 1) ^ 1) * BUF];

        bfrag a[2], b[4];

        // ---- phase 1: A rows 0-31 of wave half x B(all 64 of wave col) ----
        block_sync();
#pragma unroll
        for (int m = 0; m < 2; m++) a[m] = ldsfrag(Ab, wm * 64 + m * 16 + n16, quad);
#pragma unroll
        for (int j = 0; j < 4; j++) b[j] = ldsfrag(Bb, wn * 64 + j * 16 + n16, quad);
        if (t + 1 < nt) {   // A region of other buf: last read ph2(t-1), >=1 barrier ago
            stage4k(A, lda, row0, (t + 1) * 32, AbN, 0, tid);
            stage4k(A, lda, row0, (t + 1) * 32, AbN, 1, tid);
        }
        asm volatile("s_waitcnt lgkmcnt(0)" ::: "memory");
        __builtin_amdgcn_sched_barrier(0);
        __builtin_amdgcn_s_setprio(1);
#pragma unroll
        for (int m = 0; m < 2; m++)
#pragma unroll
            for (int j = 0; j < 4; j++)
                acc[m][j] = __builtin_amdgcn_mfma_f32_16x16x32_bf16(a[m], b[j], acc[m][j], 0, 0, 0);
        __builtin_amdgcn_s_setprio(0);

        // ---- phase 2: A rows 32-63 of wave half x B(all) ----
        block_sync();
#pragma unroll
        for (int m = 0; m < 2; m++) a[m] = ldsfrag(Ab, wm * 64 + (m + 2) * 16 + n16, quad);
        if (t + 2 < nt) {   // B region of this buf freed at ph1 (one barrier ago)
            stage4k(W, K, col0, (t + 2) * 32, Bb, 0, tid);
            stage4k(W, K, col0, (t + 2) * 32, Bb, 1, tid);
        }
        asm volatile("s_waitcnt lgkmcnt(0)" ::: "memory");
        __builtin_amdgcn_sched_barrier(0);
        __builtin_amdgcn_s_setprio(1);
#pragma unroll
        for (int m = 0; m < 2; m++)
#pragma unroll
            for (int j = 0; j < 4; j++)
                acc[m + 2][j] = __builtin_amdgcn_mfma_f32_16x16x32_bf16(a[m], b[j], acc[m + 2][j], 0, 0, 0);
        __builtin_amdgcn_s_setprio(0);

        // counted checkpoint (see ledger above)
        if (t < nt - 2) { VMC(2); }
        else            { VMC(0); }
    }

    // ---- epilogue ----
    const float* bias = (col0 < 1024) ? b0p : (col0 < 2048 ? b1p : b2p);
    const float bsc   = (col0 < 1024) ? qscale : 1.0f;
    const int bcol0   = col0 & 1023;

    if (col0 < 2048 || VtOut == nullptr) {
#pragma unroll
        for (int m = 0; m < 4; m++)
#pragma unroll
            for (int j = 0; j < 4; j++)
#pragma unroll
                for (int r = 0; r < 4; r++) {
                    int row = row0 + wm * 64 + m * 16 + quad * 4 + r;
                    int col = wn * 64 + j * 16 + n16;
                    float v = acc[m][j][r] + bias[bcol0 + col] * bsc;
                    C[(size_t)row * ldc + col0 + col] = (OT)v;
                }
    } else {
        // V block: write transposed into Vt[(b*16+h)*64+d][s], packed 4 tokens
#pragma unroll
        for (int m = 0; m < 4; m++) {
#pragma unroll
            for (int j = 0; j < 4; j++) {
                int dg     = col0 + wn * 64 + j * 16 + n16 - 2048;   // 0..1023
                int token0 = row0 + wm * 64 + m * 16 + quad * 4;
                int bb     = token0 >> 12;
                float bv   = bias[bcol0 + wn * 64 + j * 16 + n16];
                size_t vrow = ((size_t)bb * NHEAD + (dg >> 6)) * HD + (dg & 63);
                bf16x4 pk;
#pragma unroll
                for (int r = 0; r < 4; r++) pk[r] = (__bf16)(acc[m][j][r] + bv);
                *(bf16x4*)&VtOut[vrow * SEQ + (token0 & (SEQ - 1))] = pk;
            }
        }
    }
}

// ---------------------------------------------------------------------------
// fp32 -> bf16 casts
// ---------------------------------------------------------------------------
__global__ __launch_bounds__(256)
void cast_x(const float* __restrict__ s, bf16_t* __restrict__ d)
{
    size_t i = ((size_t)blockIdx.x * 256 + threadIdx.x) * 8;
    float4 a = *(const float4*)(s + i);
    float4 b = *(const float4*)(s + i + 4);
    bfrag o;
    o[0] = (__bf16)a.x; o[1] = (__bf16)a.y; o[2] = (__bf16)a.z; o[3] = (__bf16)a.w;
    o[4] = (__bf16)b.x; o[5] = (__bf16)b.y; o[6] = (__bf16)b.z; o[7] = (__bf16)b.w;
    *(bfrag*)(d + i) = o;
}

__global__ __launch_bounds__(256)
void cast_w(const float* __restrict__ wq, const float* __restrict__ wk,
            const float* __restrict__ wv, const float* __restrict__ wo,
            bf16_t* __restrict__ d)   // d = [Wq*QSC|Wk|Wv|Wo] bf16
{
    size_t t   = (size_t)blockIdx.x * 256 + threadIdx.x;   // 0..524287
    int    sel = (int)(t >> 17);
    const float* s = sel == 0 ? wq : (sel == 1 ? wk : (sel == 2 ? wv : wo));
    const float sc = (sel == 0) ? QSC : 1.0f;   // softmax scale * log2e into Wq (exp2 domain)
    size_t off = (t & 131071) * 8;
    float4 a = *(const float4*)(s + off);
    float4 b = *(const float4*)(s + off + 4);
    bfrag o;
    o[0] = (__bf16)(a.x * sc); o[1] = (__bf16)(a.y * sc);
    o[2] = (__bf16)(a.z * sc); o[3] = (__bf16)(a.w * sc);
    o[4] = (__bf16)(b.x * sc); o[5] = (__bf16)(b.y * sc);
    o[6] = (__bf16)(b.z * sc); o[7] = (__bf16)(b.w * sc);
    *(bfrag*)(d + (size_t)sel * 1048576 + off) = o;
}

// ---------------------------------------------------------------------------
// Flash sliding-window attention, transposed frame (S^T / O^T).
// R9-verified: early-issue V (T14) at (256,2) bounds (no spill), exp2
// domain, defer-max THR=8. Unchanged this round.
// ---------------------------------------------------------------------------
__global__ __launch_bounds__(256, 2)
void attn_win(const bf16_t* __restrict__ QK, const bf16_t* __restrict__ Vt,
              bf16_t* __restrict__ AO)
{
    __shared__ __align__(16) bf16_t Ks[2][64 * 72];     // 18432 B
    __shared__ __align__(16) bf16_t Pw[4][32 * PSTR];   // 19456 B, wave-private

    const int tid  = threadIdx.x;
    const int wid  = tid >> 6;          // 0..3
    const int lane = tid & 63;
    const int n16  = lane & 15;
    const int quad = lane >> 4;

    const int lin = blockIdx.x;          // 0..1023
    const int sub = lin >> 3;            // 0..127
    const int bh  = (lin & 7) * 4 + (sub >> 5);
    const int qt  = sub & 31;
    const int qb0 = qt * 128;

    const int b  = bh >> 4, h = bh & 15;
    const size_t bS   = (size_t)b * SEQ;
    const size_t hoff = (size_t)h * HD;
    const bf16_t* Vb  = Vt + (size_t)bh * HD * SEQ;   // [d][s]
    const int wstart  = qb0 - 512;
    const int it0     = (qb0 < 512) ? ((512 - qb0) >> 6) : 0;

    const int srow  = tid >> 2;
    const int scol0 = (tid & 3) * 16;

    const int qwmin = qb0 + wid * 32;
    const int qwmax = qwmin + 31;
    int qa[2];
    bfrag bq0[2], bq1[2];
#pragma unroll
    for (int qg = 0; qg < 2; qg++) {
        qa[qg] = qwmin + qg * 16 + n16;
        bq0[qg] = *(const bfrag*)(&QK[(bS + qa[qg]) * LQK + hoff + quad * 8]);
        bq1[qg] = *(const bfrag*)(&QK[(bS + qa[qg]) * LQK + hoff + 32 + quad * 8]);
    }

    f32x4 ao[2][4];
#pragma unroll
    for (int qg = 0; qg < 2; qg++)
#pragma unroll
        for (int j = 0; j < 4; j++) ao[qg][j] = (f32x4){0.f, 0.f, 0.f, 0.f};
    float m[2] = {-1e30f, -1e30f}, l[2] = {0.f, 0.f};

    uint4 kp0, kp1;
    {
        const bf16_t* src = &QK[(bS + wstart + it0 * 64 + srow) * LQK + 1024 + hoff + scol0];
        kp0 = *(const uint4*)(src);
        kp1 = *(const uint4*)(src + 8);
    }

    for (int it = it0; it < 10; ++it) {
        const int k0 = wstart + it * 64;
        const int pb = it & 1;
        *(uint4*)(&Ks[pb][srow * 72 + scol0])     = kp0;
        *(uint4*)(&Ks[pb][srow * 72 + scol0 + 8]) = kp1;
        __syncthreads();
        if (it < 9) {
            const bf16_t* src = &QK[(bS + wstart + (it + 1) * 64 + srow) * LQK + 1024 + hoff + scol0];
            kp0 = *(const uint4*)(src);
            kp1 = *(const uint4*)(src + 8);
        }

        if (k0 > qwmax || k0 + 63 < qwmin - 511) continue;

        // ---- early-issue V loads: consumed in PV, ~full QK+softmax later ----
        bfrag vf[2][4];
#pragma unroll
        for (int ks = 0; ks < 2; ks++)
#pragma unroll
            for (int j = 0; j < 4; j++)
                vf[ks][j] = *(const bfrag*)(&Vb[(size_t)(j * 16 + n16) * SEQ
                                                + k0 + ks * 32 + quad * 8]);

        // ---- S^T = K Q^T ----
        f32x4 a[2][4];
#pragma unroll
        for (int nt = 0; nt < 4; nt++) {
            bfrag ak0 = *(const bfrag*)(&Ks[pb][(nt * 16 + n16) * 72 + quad * 8]);
            bfrag ak1 = *(const bfrag*)(&Ks[pb][(nt * 16 + n16) * 72 + 32 + quad * 8]);
#pragma unroll
            for (int qg = 0; qg < 2; qg++) {
                f32x4 s4 = (f32x4){0.f, 0.f, 0.f, 0.f};
                s4 = __builtin_amdgcn_mfma_f32_16x16x32_bf16(ak0, bq0[qg], s4, 0, 0, 0);
                s4 = __builtin_amdgcn_mfma_f32_16x16x32_bf16(ak1, bq1[qg], s4, 0, 0, 0);
                a[qg][nt] = s4;
            }
        }

#pragma unroll
        for (int qg = 0; qg < 2; qg++) {
            const int gmin = qwmin + qg * 16, gmax = gmin + 15;
            const bool msk = !((k0 >= gmax - 511) & (k0 + 63 <= gmin));
            if (msk) {
#pragma unroll
                for (int nt = 0; nt < 4; nt++)
#pragma unroll
                    for (int r = 0; r < 4; r++) {
                        int ka = k0 + nt * 16 + quad * 4 + r;
                        bool valid = (ka >= qa[qg] - 511) & (ka <= qa[qg]);
                        if (!valid) a[qg][nt][r] = -1e30f;
                    }
            }

            // online softmax (exp2 domain), defer-max THR=8
            float cm = -1e30f;
#pragma unroll
            for (int nt = 0; nt < 4; nt++)
#pragma unroll
                for (int r = 0; r < 4; r++) cm = fmaxf(cm, a[qg][nt][r]);
            cm = fmaxf(cm, __shfl_xor(cm, 16, 64));
            cm = fmaxf(cm, __shfl_xor(cm, 32, 64));
            if (!__all(cm <= m[qg] + 8.f)) {
                float mn    = fmaxf(m[qg], cm);
                float alpha = EXP2(m[qg] - mn);
                m[qg] = mn;
#pragma unroll
                for (int j = 0; j < 4; j++)
#pragma unroll
                    for (int r = 0; r < 4; r++) ao[qg][j][r] *= alpha;
                l[qg] *= alpha;
            }

            float lacc = 0.f;
#pragma unroll
            for (int nt = 0; nt < 4; nt++) {
                bf16x4 pk;
#pragma unroll
                for (int r = 0; r < 4; r++) {
                    float p = EXP2(a[qg][nt][r] - m[qg]);
                    lacc += p;
                    pk[r] = (__bf16)p;
                }
                *(bf16x4*)&Pw[wid][(qg * 16 + n16) * PSTR + nt * 16 + quad * 4] = pk;
            }
            l[qg] += lacc;
        }

        // ---- O^T += V^T P^T (V frags pre-loaded) ----
#pragma unroll
        for (int ks = 0; ks < 2; ks++) {
            bfrag bp[2];
#pragma unroll
            for (int qg = 0; qg < 2; qg++)
                bp[qg] = *(const bfrag*)(&Pw[wid][(qg * 16 + n16) * PSTR + ks * 32 + quad * 8]);
#pragma unroll
            for (int j = 0; j < 4; j++) {
#pragma unroll
                for (int qg = 0; qg < 2; qg++)
                    ao[qg][j] = __builtin_amdgcn_mfma_f32_16x16x32_bf16(vf[ks][j], bp[qg], ao[qg][j], 0, 0, 0);
            }
        }
    }

#pragma unroll
    for (int qg = 0; qg < 2; qg++) {
        float lv = l[qg];
        lv += __shfl_xor(lv, 16, 64);
        lv += __shfl_xor(lv, 32, 64);
        const float inv = 1.0f / lv;
#pragma unroll
        for (int j = 0; j < 4; j++) {
            bf16x4 pk;
#pragma unroll
            for (int r = 0; r < 4; r++) pk[r] = (__bf16)(ao[qg][j][r] * inv);
            *(bf16x4*)&AO[(bS + qa[qg]) * NDIM + hoff + j * 16 + quad * 4] = pk;
        }
    }
}

// ---------------------------------------------------------------------------
extern "C" void kernel_launch(void* const* d_in, const int* in_sizes, int n_in,
                              void* d_out, int out_size, void* d_ws, size_t ws_size,
                              hipStream_t stream)
{
    const float* x  = (const float*)d_in[0];
    const float* Wq = (const float*)d_in[1];
    const float* bq = (const float*)d_in[2];
    const float* Wk = (const float*)d_in[3];
    const float* bk = (const float*)d_in[4];
    const float* Wv = (const float*)d_in[5];
    const float* bv = (const float*)d_in[6];
    const float* Wo = (const float*)d_in[7];
    const float* bo = (const float*)d_in[8];
    float* out = (float*)d_out;

    const size_t QK_E = (size_t)MROWS * LQK;
    const size_t X_E  = (size_t)MROWS * NDIM;
    if (ws_size < (QK_E + X_E + 4u * 1048576u) * sizeof(bf16_t)) return;

    bf16_t* QKb = (bf16_t*)d_ws;
    bf16_t* AbX = QKb + QK_E;
    bf16_t* Wc  = AbX + X_E;
    bf16_t* Wob = Wc + 3u * 1048576u;
    bf16_t* Vtg = (bf16_t*)d_out;   // scratch inside out buf; dead before O-proj

    dim3 blk(256);

    cast_x<<<dim3(4096), blk, 0, stream>>>(x, AbX);
    cast_w<<<dim3(2048), blk, 0, stream>>>(Wq, Wk, Wv, Wo, Wc);

    // fused QKV projection: 128x128 4-wave, 4 blocks/CU.
    // grid 1536 = 64 row-blocks x 24 col-blocks, flat; 1536 % 8 == 0.
    gemm4w<bf16_t><<<dim3(1536), blk, 0, stream>>>(
        AbX, NDIM, Wc, bq, bk, bv, QSC, QKb, LQK, NDIM, Vtg, 24);

    attn_win<<<dim3(1024), dim3(256), 0, stream>>>(QKb, Vtg, AbX);

    // output projection: 128x128 4-wave (grid 512 = 64 x 8, 4/CU).
    gemm4w<float><<<dim3(512), blk, 0, stream>>>(
        AbX, NDIM, Wob, bo, bo, bo, 1.0f, out, NDIM, NDIM, nullptr, 8);
}

// Round 11
// 232.334 us; speedup vs baseline: 1.0468x; 1.0468x over previous
//
#include <hip/hip_runtime.h>
#include <hip/hip_bf16.h>
#include <cmath>

typedef __bf16 bf16_t;
typedef __attribute__((ext_vector_type(8))) __bf16 bfrag;   // 8 bf16 = 4 VGPRs (MFMA A/B frag)
typedef __attribute__((ext_vector_type(4))) __bf16 bf16x4;  // 8B packed store
typedef __attribute__((ext_vector_type(4))) float f32x4;    // MFMA C/D frag

#define SEQ    4096
#define NDIM   1024
#define NHEAD  16
#define HD     64
#define NBATCH 2
#define MROWS  (NBATCH * SEQ)   // 8192
#define LQK    2048             // fused Q|K row stride
#define PSTR   76               // Pw key-stride (conflict-free b64 writes)
// softmax scale 1/8 times log2(e): scores land in exp2 domain (R7)
#define QSC    0.1803368801111f
// exp2f lowers to v_exp_f32 (gfx950 exp IS base-2); __exp2f does not exist in HIP
#define EXP2(x) exp2f(x)

// async 16B global -> LDS (m97 pattern). l must be wave-uniform; lane i lands at l + i*16.
__device__ __forceinline__ void gload_lds16(const bf16_t* g, bf16_t* l) {
    __builtin_amdgcn_global_load_lds(
        (const __attribute__((address_space(1))) unsigned int*)g,
        (__attribute__((address_space(3))) unsigned int*)l,
        16, 0, 0);
}

// raw workgroup barrier WITHOUT the vmcnt(0)/lgkmcnt(0) drain of __syncthreads.
__device__ __forceinline__ void block_sync() {
    asm volatile("" ::: "memory");
    __builtin_amdgcn_s_barrier();
    asm volatile("" ::: "memory");
}
#define VMC(n)  asm volatile("s_waitcnt vmcnt(" #n ")" ::: "memory")

// stage 8 KiB (128 rows x 64 B) of a [*, 32-el] LDS region: linear DMA dest,
// pre-swizzled global source (swizzle byte ^= ((byte>>9)&1)<<5). half=0 -> rows
// 0..127, half=1 -> rows 128..255. One gload_lds16 per thread per call (512 thr).
// (R1/R5-verified verbatim.)
__device__ __forceinline__ void stage_half(const bf16_t* __restrict__ G, int ldg,
                                           int grow0, int gk0, bf16_t* region,
                                           int half, int tid)
{
    const int poff = half * 8192 + tid * 16;            // dest byte in region (linear)
    const int loff = poff ^ (((poff >> 9) & 1) << 5);   // logical byte (pre-swizzled src)
    const int r    = loff >> 6;                         // row (64 B rows)
    const int cb   = loff & 63;
    const bf16_t* src = G + (size_t)(grow0 + r) * ldg + gk0 + (cb >> 1);
    gload_lds16(src, region + ((half * 8192 + (tid >> 6) * 1024) >> 1));
}

__device__ __forceinline__ bfrag ldsfrag(const bf16_t* region, int R, int quad)
{
    const int off = (R * 64 + quad * 16) ^ (((R >> 3) & 1) << 5);   // bytes
    return *(const bfrag*)((const char*)region + off);
}

// ---------------------------------------------------------------------------
// 2-phase 128x256 GEMM, 2 blocks/CU (R6/R9-verified; QKV best-measured 68 us,
// 757 TF). Occupancy ladder measured across R5-R10: 1 blk/CU (256^2) = 75-81,
// 2 blk/CU (this) = 68, 4 blk/CU (128^2 4-wave) = 76 -> this is the optimum;
// 3 blk/CU impossible (acc 64 regs + 56 VGPR = 120/thread caps 16 waves/CU).
// ---------------------------------------------------------------------------
template <typename OT>
__global__ __launch_bounds__(512, 4)
void gemm2ph(const bf16_t* __restrict__ A, int lda,
             const bf16_t* __restrict__ W,
             const float* __restrict__ b0p, const float* __restrict__ b1p,
             const float* __restrict__ b2p, float qscale,
             OT* __restrict__ C, int ldc, int K,
             bf16_t* __restrict__ VtOut, int nbx)
{
    constexpr int ABUF = 4096;        // A els per buf (128 rows x 32)
    constexpr int BBUF = 8192;        // B els per buf (256 rows x 32)
    constexpr int BUF  = ABUF + BBUF;
    __shared__ __align__(1024) bf16_t LSD[2 * BUF];   // 48 KiB

    const int tid  = threadIdx.x;
    const int lane = tid & 63;
    const int n16  = lane & 15;
    const int quad = lane >> 4;
    const int wid  = tid >> 6;
    const int wm   = wid >> 2;            // 0..1 (64-row half)
    const int wn   = wid & 3;             // 0..3 (64-col quarter)

    // bijective XCD swizzle (nwg % 8 == 0 for both grids used)
    const int nwg = (int)gridDim.x;
    const int f   = (int)blockIdx.x;
    const int swz = (f & 7) * (nwg >> 3) + (f >> 3);
    const int bx  = swz % nbx;
    const int by  = swz / nbx;
    const int row0 = by * 128;
    const int col0 = bx * 256;
    const int nt   = K >> 5;              // K-tiles of 32 (nt >= 3)

    f32x4 acc[4][4];
#pragma unroll
    for (int m = 0; m < 4; m++)
#pragma unroll
        for (int j = 0; j < 4; j++) acc[m][j] = (f32x4){0.f, 0.f, 0.f, 0.f};

    // ---- prologue: A(0), B(0) -> buf0; B(1) -> buf1 (A(1) staged at t=0 ph1)
    {
        bf16_t* A0 = &LSD[0];
        bf16_t* B0 = &LSD[ABUF];
        bf16_t* B1 = &LSD[BUF + ABUF];
        stage_half(A, lda, row0, 0, A0, 0, tid);
        stage_half(W, K, col0, 0, B0, 0, tid);
        stage_half(W, K, col0, 0, B0, 1, tid);
        stage_half(W, K, col0, 32, B1, 0, tid);
        stage_half(W, K, col0, 32, B1, 1, tid);
    }
    VMC(2);   // A0,B0 landed (per wave); barrier at ph1 publishes across waves

    for (int t = 0; t < nt; ++t) {
        bf16_t* Ab  = &LSD[(t & 1) * BUF];
        bf16_t* Bb  = Ab + ABUF;
        bf16_t* AbN = &LSD[((t & 1) ^ 1) * BUF];

        bfrag a[2], b[4];

        // ---- phase 1: A rows 0-31 of wave half x B(all) ----
        block_sync();
#pragma unroll
        for (int m = 0; m < 2; m++) a[m] = ldsfrag(Ab, wm * 64 + m * 16 + n16, quad);
#pragma unroll
        for (int j = 0; j < 4; j++) b[j] = ldsfrag(Bb, wn * 64 + j * 16 + n16, quad);
        if (t + 1 < nt)   // A region of other buf: last read ph2(t-1), >=1 barrier ago
            stage_half(A, lda, row0, (t + 1) * 32, AbN, 0, tid);
        asm volatile("s_waitcnt lgkmcnt(0)" ::: "memory");
        __builtin_amdgcn_sched_barrier(0);
        __builtin_amdgcn_s_setprio(1);
#pragma unroll
        for (int m = 0; m < 2; m++)
#pragma unroll
            for (int j = 0; j < 4; j++)
                acc[m][j] = __builtin_amdgcn_mfma_f32_16x16x32_bf16(a[m], b[j], acc[m][j], 0, 0, 0);
        __builtin_amdgcn_s_setprio(0);

        // ---- phase 2: A rows 32-63 of wave half x B(all) ----
        block_sync();
#pragma unroll
        for (int m = 0; m < 2; m++) a[m] = ldsfrag(Ab, wm * 64 + (m + 2) * 16 + n16, quad);
        if (t + 2 < nt) {   // B region of this buf freed at ph1 (one barrier ago)
            stage_half(W, K, col0, (t + 2) * 32, Bb, 0, tid);
            stage_half(W, K, col0, (t + 2) * 32, Bb, 1, tid);
        }
        asm volatile("s_waitcnt lgkmcnt(0)" ::: "memory");
        __builtin_amdgcn_sched_barrier(0);
        __builtin_amdgcn_s_setprio(1);
#pragma unroll
        for (int m = 0; m < 2; m++)
#pragma unroll
            for (int j = 0; j < 4; j++)
                acc[m + 2][j] = __builtin_amdgcn_mfma_f32_16x16x32_bf16(a[m], b[j], acc[m + 2][j], 0, 0, 0);
        __builtin_amdgcn_s_setprio(0);

        // counted checkpoint (see R6 ledger)
        if (t < nt - 2) { VMC(2); }
        else            { VMC(0); }
    }

    // ---- epilogue ----
    const float* bias = (col0 < 1024) ? b0p : (col0 < 2048 ? b1p : b2p);
    const float bsc   = (col0 < 1024) ? qscale : 1.0f;
    const int bcol0   = col0 & 1023;

    if (col0 < 2048 || VtOut == nullptr) {
#pragma unroll
        for (int m = 0; m < 4; m++)
#pragma unroll
            for (int j = 0; j < 4; j++)
#pragma unroll
                for (int r = 0; r < 4; r++) {
                    int row = row0 + wm * 64 + m * 16 + quad * 4 + r;
                    int col = wn * 64 + j * 16 + n16;
                    float v = acc[m][j][r] + bias[bcol0 + col] * bsc;
                    C[(size_t)row * ldc + col0 + col] = (OT)v;
                }
    } else {
        // V block: write transposed into Vt[(b*16+h)*64+d][s], packed 4 tokens
#pragma unroll
        for (int m = 0; m < 4; m++) {
#pragma unroll
            for (int j = 0; j < 4; j++) {
                int dg     = col0 + wn * 64 + j * 16 + n16 - 2048;   // 0..1023
                int token0 = row0 + wm * 64 + m * 16 + quad * 4;
                int bb     = token0 >> 12;
                float bv   = bias[bcol0 + wn * 64 + j * 16 + n16];
                size_t vrow = ((size_t)bb * NHEAD + (dg >> 6)) * HD + (dg & 63);
                bf16x4 pk;
#pragma unroll
                for (int r = 0; r < 4; r++) pk[r] = (__bf16)(acc[m][j][r] + bv);
                *(bf16x4*)&VtOut[vrow * SEQ + (token0 & (SEQ - 1))] = pk;
            }
        }
    }
}

// ---------------------------------------------------------------------------
// fused fp32 -> bf16 casts: blocks 0..4095 cast x, 4096..6143 cast W's.
// Block-uniform branch (no divergence); one launch instead of two.
// ---------------------------------------------------------------------------
__global__ __launch_bounds__(256)
void cast_all(const float* __restrict__ x,
              const float* __restrict__ wq, const float* __restrict__ wk,
              const float* __restrict__ wv, const float* __restrict__ wo,
              bf16_t* __restrict__ dx, bf16_t* __restrict__ dw)
{
    const int bid = (int)blockIdx.x;
    if (bid < 4096) {
        size_t i = ((size_t)bid * 256 + threadIdx.x) * 8;
        float4 a = *(const float4*)(x + i);
        float4 b = *(const float4*)(x + i + 4);
        bfrag o;
        o[0] = (__bf16)a.x; o[1] = (__bf16)a.y; o[2] = (__bf16)a.z; o[3] = (__bf16)a.w;
        o[4] = (__bf16)b.x; o[5] = (__bf16)b.y; o[6] = (__bf16)b.z; o[7] = (__bf16)b.w;
        *(bfrag*)(dx + i) = o;
    } else {
        size_t t   = (size_t)(bid - 4096) * 256 + threadIdx.x;   // 0..524287
        int    sel = (int)(t >> 17);
        const float* s = sel == 0 ? wq : (sel == 1 ? wk : (sel == 2 ? wv : wo));
        const float sc = (sel == 0) ? QSC : 1.0f;   // softmax scale * log2e into Wq (exp2 domain)
        size_t off = (t & 131071) * 8;
        float4 a = *(const float4*)(s + off);
        float4 b = *(const float4*)(s + off + 4);
        bfrag o;
        o[0] = (__bf16)(a.x * sc); o[1] = (__bf16)(a.y * sc);
        o[2] = (__bf16)(a.z * sc); o[3] = (__bf16)(a.w * sc);
        o[4] = (__bf16)(b.x * sc); o[5] = (__bf16)(b.y * sc);
        o[6] = (__bf16)(b.z * sc); o[7] = (__bf16)(b.w * sc);
        *(bfrag*)(dw + (size_t)sel * 1048576 + off) = o;
    }
}

// ---------------------------------------------------------------------------
// Flash sliding-window attention, transposed frame (S^T / O^T).
// R9-verified: early-issue V (T14) at (256,2) bounds (no spill), exp2
// domain, defer-max THR=8. Unchanged.
// ---------------------------------------------------------------------------
__global__ __launch_bounds__(256, 2)
void attn_win(const bf16_t* __restrict__ QK, const bf16_t* __restrict__ Vt,
              bf16_t* __restrict__ AO)
{
    __shared__ __align__(16) bf16_t Ks[2][64 * 72];     // 18432 B
    __shared__ __align__(16) bf16_t Pw[4][32 * PSTR];   // 19456 B, wave-private

    const int tid  = threadIdx.x;
    const int wid  = tid >> 6;          // 0..3
    const int lane = tid & 63;
    const int n16  = lane & 15;
    const int quad = lane >> 4;

    const int lin = blockIdx.x;          // 0..1023
    const int sub = lin >> 3;            // 0..127
    const int bh  = (lin & 7) * 4 + (sub >> 5);
    const int qt  = sub & 31;
    const int qb0 = qt * 128;

    const int b  = bh >> 4, h = bh & 15;
    const size_t bS   = (size_t)b * SEQ;
    const size_t hoff = (size_t)h * HD;
    const bf16_t* Vb  = Vt + (size_t)bh * HD * SEQ;   // [d][s]
    const int wstart  = qb0 - 512;
    const int it0     = (qb0 < 512) ? ((512 - qb0) >> 6) : 0;

    const int srow  = tid >> 2;
    const int scol0 = (tid & 3) * 16;

    const int qwmin = qb0 + wid * 32;
    const int qwmax = qwmin + 31;
    int qa[2];
    bfrag bq0[2], bq1[2];
#pragma unroll
    for (int qg = 0; qg < 2; qg++) {
        qa[qg] = qwmin + qg * 16 + n16;
        bq0[qg] = *(const bfrag*)(&QK[(bS + qa[qg]) * LQK + hoff + quad * 8]);
        bq1[qg] = *(const bfrag*)(&QK[(bS + qa[qg]) * LQK + hoff + 32 + quad * 8]);
    }

    f32x4 ao[2][4];
#pragma unroll
    for (int qg = 0; qg < 2; qg++)
#pragma unroll
        for (int j = 0; j < 4; j++) ao[qg][j] = (f32x4){0.f, 0.f, 0.f, 0.f};
    float m[2] = {-1e30f, -1e30f}, l[2] = {0.f, 0.f};

    uint4 kp0, kp1;
    {
        const bf16_t* src = &QK[(bS + wstart + it0 * 64 + srow) * LQK + 1024 + hoff + scol0];
        kp0 = *(const uint4*)(src);
        kp1 = *(const uint4*)(src + 8);
    }

    for (int it = it0; it < 10; ++it) {
        const int k0 = wstart + it * 64;
        const int pb = it & 1;
        *(uint4*)(&Ks[pb][srow * 72 + scol0])     = kp0;
        *(uint4*)(&Ks[pb][srow * 72 + scol0 + 8]) = kp1;
        __syncthreads();
        if (it < 9) {
            const bf16_t* src = &QK[(bS + wstart + (it + 1) * 64 + srow) * LQK + 1024 + hoff + scol0];
            kp0 = *(const uint4*)(src);
            kp1 = *(const uint4*)(src + 8);
        }

        if (k0 > qwmax || k0 + 63 < qwmin - 511) continue;

        // ---- early-issue V loads: consumed in PV, ~full QK+softmax later ----
        bfrag vf[2][4];
#pragma unroll
        for (int ks = 0; ks < 2; ks++)
#pragma unroll
            for (int j = 0; j < 4; j++)
                vf[ks][j] = *(const bfrag*)(&Vb[(size_t)(j * 16 + n16) * SEQ
                                                + k0 + ks * 32 + quad * 8]);

        // ---- S^T = K Q^T ----
        f32x4 a[2][4];
#pragma unroll
        for (int nt = 0; nt < 4; nt++) {
            bfrag ak0 = *(const bfrag*)(&Ks[pb][(nt * 16 + n16) * 72 + quad * 8]);
            bfrag ak1 = *(const bfrag*)(&Ks[pb][(nt * 16 + n16) * 72 + 32 + quad * 8]);
#pragma unroll
            for (int qg = 0; qg < 2; qg++) {
                f32x4 s4 = (f32x4){0.f, 0.f, 0.f, 0.f};
                s4 = __builtin_amdgcn_mfma_f32_16x16x32_bf16(ak0, bq0[qg], s4, 0, 0, 0);
                s4 = __builtin_amdgcn_mfma_f32_16x16x32_bf16(ak1, bq1[qg], s4, 0, 0, 0);
                a[qg][nt] = s4;
            }
        }

#pragma unroll
        for (int qg = 0; qg < 2; qg++) {
            const int gmin = qwmin + qg * 16, gmax = gmin + 15;
            const bool msk = !((k0 >= gmax - 511) & (k0 + 63 <= gmin));
            if (msk) {
#pragma unroll
                for (int nt = 0; nt < 4; nt++)
#pragma unroll
                    for (int r = 0; r < 4; r++) {
                        int ka = k0 + nt * 16 + quad * 4 + r;
                        bool valid = (ka >= qa[qg] - 511) & (ka <= qa[qg]);
                        if (!valid) a[qg][nt][r] = -1e30f;
                    }
            }

            // online softmax (exp2 domain), defer-max THR=8
            float cm = -1e30f;
#pragma unroll
            for (int nt = 0; nt < 4; nt++)
#pragma unroll
                for (int r = 0; r < 4; r++) cm = fmaxf(cm, a[qg][nt][r]);
            cm = fmaxf(cm, __shfl_xor(cm, 16, 64));
            cm = fmaxf(cm, __shfl_xor(cm, 32, 64));
            if (!__all(cm <= m[qg] + 8.f)) {
                float mn    = fmaxf(m[qg], cm);
                float alpha = EXP2(m[qg] - mn);
                m[qg] = mn;
#pragma unroll
                for (int j = 0; j < 4; j++)
#pragma unroll
                    for (int r = 0; r < 4; r++) ao[qg][j][r] *= alpha;
                l[qg] *= alpha;
            }

            float lacc = 0.f;
#pragma unroll
            for (int nt = 0; nt < 4; nt++) {
                bf16x4 pk;
#pragma unroll
                for (int r = 0; r < 4; r++) {
                    float p = EXP2(a[qg][nt][r] - m[qg]);
                    lacc += p;
                    pk[r] = (__bf16)p;
                }
                *(bf16x4*)&Pw[wid][(qg * 16 + n16) * PSTR + nt * 16 + quad * 4] = pk;
            }
            l[qg] += lacc;
        }

        // ---- O^T += V^T P^T (V frags pre-loaded) ----
#pragma unroll
        for (int ks = 0; ks < 2; ks++) {
            bfrag bp[2];
#pragma unroll
            for (int qg = 0; qg < 2; qg++)
                bp[qg] = *(const bfrag*)(&Pw[wid][(qg * 16 + n16) * PSTR + ks * 32 + quad * 8]);
#pragma unroll
            for (int j = 0; j < 4; j++) {
#pragma unroll
                for (int qg = 0; qg < 2; qg++)
                    ao[qg][j] = __builtin_amdgcn_mfma_f32_16x16x32_bf16(vf[ks][j], bp[qg], ao[qg][j], 0, 0, 0);
            }
        }
    }

#pragma unroll
    for (int qg = 0; qg < 2; qg++) {
        float lv = l[qg];
        lv += __shfl_xor(lv, 16, 64);
        lv += __shfl_xor(lv, 32, 64);
        const float inv = 1.0f / lv;
#pragma unroll
        for (int j = 0; j < 4; j++) {
            bf16x4 pk;
#pragma unroll
            for (int r = 0; r < 4; r++) pk[r] = (__bf16)(ao[qg][j][r] * inv);
            *(bf16x4*)&AO[(bS + qa[qg]) * NDIM + hoff + j * 16 + quad * 4] = pk;
        }
    }
}

// ---------------------------------------------------------------------------
extern "C" void kernel_launch(void* const* d_in, const int* in_sizes, int n_in,
                              void* d_out, int out_size, void* d_ws, size_t ws_size,
                              hipStream_t stream)
{
    const float* x  = (const float*)d_in[0];
    const float* Wq = (const float*)d_in[1];
    const float* bq = (const float*)d_in[2];
    const float* Wk = (const float*)d_in[3];
    const float* bk = (const float*)d_in[4];
    const float* Wv = (const float*)d_in[5];
    const float* bv = (const float*)d_in[6];
    const float* Wo = (const float*)d_in[7];
    const float* bo = (const float*)d_in[8];
    float* out = (float*)d_out;

    const size_t QK_E = (size_t)MROWS * LQK;
    const size_t X_E  = (size_t)MROWS * NDIM;
    if (ws_size < (QK_E + X_E + 4u * 1048576u) * sizeof(bf16_t)) return;

    bf16_t* QKb = (bf16_t*)d_ws;
    bf16_t* AbX = QKb + QK_E;
    bf16_t* Wc  = AbX + X_E;
    bf16_t* Wob = Wc + 3u * 1048576u;
    bf16_t* Vtg = (bf16_t*)d_out;   // scratch inside out buf; dead before O-proj

    // fused casts: one launch (blocks 0..4095 -> x, 4096..6143 -> W's)
    cast_all<<<dim3(6144), dim3(256), 0, stream>>>(x, Wq, Wk, Wv, Wo, AbX, Wc);

    // fused QKV projection: 2-phase 128x256, 2 blocks/CU (best-measured).
    // grid 768 = 64 row-blocks x 12 col-blocks, flat; 768 % 8 == 0.
    gemm2ph<bf16_t><<<dim3(768), dim3(512), 0, stream>>>(
        AbX, NDIM, Wc, bq, bk, bv, QSC, QKb, LQK, NDIM, Vtg, 12);

    attn_win<<<dim3(1024), dim3(256), 0, stream>>>(QKb, Vtg, AbX);

    // output projection: 2-phase 128x256 (grid 256 = 64 x 4).
    gemm2ph<float><<<dim3(256), dim3(512), 0, stream>>>(
        AbX, NDIM, Wob, bo, bo, bo, 1.0f, out, NDIM, NDIM, nullptr, 4);
}